// Round 6
// baseline (229.195 us; speedup 1.0000x reference)
//
#include <hip/hip_runtime.h>
#include <cstdint>

// ---------------------------------------------------------------------------
// SAGAN self-attention block, bf16-MFMA pipeline, flash-fused attention.
// GEMMs are NT form: C[m,n] = sum_k Arow[m][k] * Brow[n][k].
// Verified fragment conventions (R2-passing gemm):
//   A-frag: lane holds A[row = lane&15][k = (lane>>4)*8 + q], q=0..7
//   B-frag: lane holds B[col = lane&15][k = (lane>>4)*8 + q]
//   C/D:    lane holds C[row = (lane>>4)*4 + r][col = lane&15], r=0..3
// ---------------------------------------------------------------------------

typedef short s8v __attribute__((ext_vector_type(8)));   // 8 bf16 bits (4 VGPR)
typedef float f32x4 __attribute__((ext_vector_type(4)));

#define DEVI static __device__ __forceinline__

DEVI unsigned short f2bf(float f) {
  union { float f; uint32_t u; } x; x.f = f;
  uint32_t u = x.u;
  return (unsigned short)((u + 0x7fffu + ((u >> 16) & 1u)) >> 16);  // RNE
}

DEVI void gl_lds16(const void* g, void* l) {
  // async global->LDS, 16B per lane; LDS dest must be wave-uniform base.
  __builtin_amdgcn_global_load_lds(
      (const __attribute__((address_space(1))) void*)g,
      (__attribute__((address_space(3))) void*)l,
      16, 0, 0);
}

// Stage a [64 rows][32 k] bf16 tile (4KB), linear LDS layout (gemm_nt).
DEVI void stage(const unsigned short* src, int ld, unsigned short* lds, int t) {
  gl_lds16(src + (long)(t >> 2) * ld + (t & 3) * 8, lds + (t >> 6) * 512);
}

// Swizzled stage: LDS slot (row, chunk c) holds global chunk c ^ ((row>>1)&3).
// Achieved by pre-swizzling the per-lane GLOBAL source (LDS dest stays linear,
// as global_load_lds requires). Readers use ksw = ((lane>>4)^((rl>>1)&3))<<3.
DEVI void stage_s(const unsigned short* src, int ld, unsigned short* lds,
                  int tt) {
  const int tr = tt >> 2, c = tt & 3;
  const int sc = (c ^ ((tr >> 1) & 3)) * 8;
  gl_lds16(src + (long)tr * ld + sc, lds + (tt >> 6) * 512);
}

// ---------------------------------------------------------------------------
// NT GEMM: 128x128 tile, 4 waves (2x2), each wave 64x64 = 4x4 frags of
// 16x16x32 bf16 MFMA. (Unchanged from R2/R3 passing version.)
// ---------------------------------------------------------------------------
template <int OBF, int BIAS, int PEM, int SILU>
__global__ __launch_bounds__(256) void gemm_nt(
    const unsigned short* __restrict__ A, const unsigned short* __restrict__ B,
    void* __restrict__ Cp, int K, int N, int ld, long sA, long sB, long sC,
    const float* __restrict__ bias, const float* __restrict__ pe, float scale) {
  const int bz = blockIdx.z;
  const unsigned short* Ab = A + (long)bz * sA;
  const unsigned short* Bb = B + (long)bz * sB;
  const int m0 = blockIdx.x * 128, n0 = blockIdx.y * 128;
  __shared__ __align__(16) unsigned short As[4096], Bs[4096];  // [128][32]
  const int t = threadIdx.x;
  const int wave = t >> 6, lane = t & 63;
  const int wr = wave >> 1, wc = wave & 1;

  f32x4 acc[4][4];
#pragma unroll
  for (int i = 0; i < 4; i++)
#pragma unroll
    for (int j = 0; j < 4; j++) acc[i][j] = f32x4{0.f, 0.f, 0.f, 0.f};

  const int rl = lane & 15, kp = (lane >> 4) * 8;

  for (int k0 = 0; k0 < K; k0 += 32) {
    stage(Ab + (long)m0 * ld + k0, ld, As, t);
    stage(Ab + (long)(m0 + 64) * ld + k0, ld, As + 2048, t);
    stage(Bb + (long)n0 * ld + k0, ld, Bs, t);
    stage(Bb + (long)(n0 + 64) * ld + k0, ld, Bs + 2048, t);
    __syncthreads();  // drains vmcnt before barrier -> LDS valid

    s8v af[4], bfr[4];
#pragma unroll
    for (int i = 0; i < 4; i++)
      af[i] = *(const s8v*)(As + (wr * 64 + i * 16 + rl) * 32 + kp);
#pragma unroll
    for (int j = 0; j < 4; j++)
      bfr[j] = *(const s8v*)(Bs + (wc * 64 + j * 16 + rl) * 32 + kp);
#pragma unroll
    for (int i = 0; i < 4; i++)
#pragma unroll
      for (int j = 0; j < 4; j++)
        acc[i][j] = __builtin_amdgcn_mfma_f32_16x16x32_bf16(af[i], bfr[j],
                                                            acc[i][j], 0, 0, 0);
    __syncthreads();
  }

  const long cb = (long)bz * sC;
#pragma unroll
  for (int i = 0; i < 4; i++) {
    const int r0 = m0 + wr * 64 + i * 16 + (lane >> 4) * 4;
#pragma unroll
    for (int j = 0; j < 4; j++) {
      const int col = n0 + wc * 64 + j * 16 + (lane & 15);
#pragma unroll
      for (int r = 0; r < 4; r++) {
        const int row = r0 + r;
        float val = acc[i][j][r] * scale;
        if (BIAS == 1) val += bias[row];
        if (BIAS == 2) val += bias[col];
        if (PEM == 1) val += pe[(long)row * 4096 + col];
        if (PEM == 2) val += pe[(long)col * 4096 + row];
        if (SILU) val = val / (1.0f + __expf(-val));
        const long ci = cb + (long)row * N + col;
        if (OBF)
          ((unsigned short*)Cp)[ci] = f2bf(val);
        else
          ((float*)Cp)[ci] = val;
      }
    }
  }
}

// ---------------------------------------------------------------------------
// Flash-fused attention v3: same compute/layout as v2 (verified), but the
// barrier schedule is counted-vmcnt (T4): 3 RAW s_barriers per iter, never
// draining the next-tile prefetch. Per iter each thread issues 8 gl_lds for
// tile n+1, then waits vmcnt(8) (= tile n's loads done, n+1's in flight).
// Mid barrier waits lgkmcnt(0) only (pL visibility), NOT vmcnt.
// ---------------------------------------------------------------------------
__global__ __launch_bounds__(512, 2) void flash_attn(
    const unsigned short* __restrict__ qTp, const unsigned short* __restrict__ kTp,
    const unsigned short* __restrict__ vBp, unsigned short* __restrict__ rTp) {
  const int bid = blockIdx.x;
  // XCD-aware mapping (perf heuristic only): 2 XCDs per batch -> per-XCD L2
  // working set = one batch's qT+vB = 4MB (fits 4MB XCD L2).
  const int xcd = bid & 7;
  const int b = xcd >> 1;
  const int j0 = ((bid >> 3) + (xcd & 1) * 32) * 64;
  const long S = 1048576;
  const unsigned short* q = qTp + (long)b * S;
  const unsigned short* k = kTp + (long)b * S;
  const unsigned short* v = vBp + (long)b * S;
  unsigned short* rT = rTp + (long)b * S;

  __shared__ __align__(16) unsigned short qL[2][16384];  // [buf][8s][64 i][32]
  __shared__ __align__(16) unsigned short vL[2][16384];  // [buf][4cg][2ki][64c][32]
  __shared__ __align__(16) unsigned short pL[4096];      // [4w][2ki][16 j][32 i]

  const int t = threadIdx.x;
  const int wave = t >> 6, lane = t & 63;
  const int h = wave >> 2, w = wave & 3;
  const int rl = lane & 15;
  const int ksw = (((lane >> 4) ^ ((rl >> 1) & 3)) << 3);  // swizzled k-offset
  const int th = t >> 8, tt = t & 255;                     // staging split

  // K-strip -> registers: wave (h,w) only ever needs rows j0 + w*16 + rl.
  const unsigned short* krow = k + (long)(j0 + w * 16 + rl) * 256 +
                               (lane >> 4) * 8;
  s8v kreg[8];
#pragma unroll
  for (int s = 0; s < 8; s++) kreg[s] = *(const s8v*)(krow + s * 32);

  f32x4 oacc[8];
#pragma unroll
  for (int f = 0; f < 8; f++) oacc[f] = f32x4{0.f, 0.f, 0.f, 0.f};
  float lsum[4] = {0.f, 0.f, 0.f, 0.f};

  // Stage (qL,vL) for i-tile `it` into buffer `bf`: 8 gl_lds per thread.
#define STAGE_QV(it, bf)                                                     \
  {                                                                          \
    const long i0_ = (long)(it) * 64;                                        \
    _Pragma("unroll") for (int ss = 0; ss < 4; ss++) {                       \
      const int s_ = ss * 2 + th;                                            \
      stage_s(q + i0_ * 256 + s_ * 32, 256, qL[bf] + s_ * 2048, tt);         \
    }                                                                        \
    _Pragma("unroll") for (int ss = 0; ss < 4; ss++) {                       \
      const int vt_ = ss * 2 + th;                                           \
      stage_s(v + (long)((vt_ >> 1) * 64) * 4096 + i0_ + (vt_ & 1) * 32,     \
              4096, vL[bf] + vt_ * 2048, tt);                                \
    }                                                                        \
  }

  STAGE_QV(0, 0)

  for (int n = 0; n < 64; ++n) {
    const int cur = n & 1;
    // B1: all waves done reading buf[cur^1] (prev iter's PV) -> reuse safe.
    asm volatile("" ::: "memory");
    __builtin_amdgcn_s_barrier();
    asm volatile("" ::: "memory");
    // Issue next tile's 8 loads (iter 63 redundantly re-stages tile 0 to
    // keep the vmcnt count uniform; it is never consumed).
    STAGE_QV((n + 1) & 63, cur ^ 1)
    // Wait for OWN 8 loads of buf[cur] (issued last iter); next-tile loads
    // remain in flight across the entire iteration (no drain).
    asm volatile("s_waitcnt vmcnt(8)" ::: "memory");
    __builtin_amdgcn_sched_barrier(0);
    __builtin_amdgcn_s_barrier();  // B2: buf[cur] complete for ALL waves
    asm volatile("" ::: "memory");

    // QK^T: sa[f] covers i-cols (2h+f)*16 + rl of this tile.
    f32x4 sa[2];
    sa[0] = f32x4{0.f, 0.f, 0.f, 0.f};
    sa[1] = f32x4{0.f, 0.f, 0.f, 0.f};
    const int R0 = (2 * h) * 16 + rl, R1 = (2 * h + 1) * 16 + rl;
    __builtin_amdgcn_s_setprio(1);
#pragma unroll
    for (int s = 0; s < 8; s++) {
      const unsigned short* qb = qL[cur] + s * 2048;
      s8v bf0 = *(const s8v*)(qb + R0 * 32 + ksw);
      s8v bf1 = *(const s8v*)(qb + R1 * 32 + ksw);
      sa[0] = __builtin_amdgcn_mfma_f32_16x16x32_bf16(kreg[s], bf0, sa[0], 0, 0, 0);
      sa[1] = __builtin_amdgcn_mfma_f32_16x16x32_bf16(kreg[s], bf1, sa[1], 0, 0, 0);
    }
    __builtin_amdgcn_s_setprio(0);

    // Static-max softmax: P = exp(s/16); accumulate partial row sums.
#pragma unroll
    for (int r = 0; r < 4; r++) {
      const float p0 = __expf(sa[0][r] * 0.0625f);
      const float p1 = __expf(sa[1][r] * 0.0625f);
      float ps = p0 + p1;
      ps += __shfl_xor(ps, 1);
      ps += __shfl_xor(ps, 2);
      ps += __shfl_xor(ps, 4);
      ps += __shfl_xor(ps, 8);
      lsum[r] += ps;
      // pL write (swizzled): row j, ki = h, cols f*16+rl.
      const int j = (lane >> 4) * 4 + r;
      const int a0 = w * 1024 + h * 512 + j * 32 +
                     ((((rl >> 3) ^ ((j >> 1) & 3))) << 3) + (rl & 7);
      pL[a0] = f2bf(p0);
      pL[a0 ^ 16] = f2bf(p1);  // chunk xor 2 <=> elem offset xor 16
    }
    // B3: pL visible across waves. LDS-only wait; prefetch stays in flight.
    asm volatile("s_waitcnt lgkmcnt(0)" ::: "memory");
    __builtin_amdgcn_sched_barrier(0);
    __builtin_amdgcn_s_barrier();
    asm volatile("" ::: "memory");

    // PV: O[16 j][128 c-half] += P[16 j][64 i] * V.
    __builtin_amdgcn_s_setprio(1);
#pragma unroll
    for (int ki = 0; ki < 2; ki++) {
      s8v pa = *(const s8v*)(pL + w * 1024 + ki * 512 + rl * 32 + ksw);
#pragma unroll
      for (int m = 0; m < 8; m++) {
        const int f2 = h * 8 + m;
        s8v vb = *(const s8v*)(vL[cur] + (f2 >> 2) * 4096 + ki * 2048 +
                               ((f2 & 3) * 16 + rl) * 32 + ksw);
        oacc[m] = __builtin_amdgcn_mfma_f32_16x16x32_bf16(pa, vb, oacc[m],
                                                          0, 0, 0);
      }
    }
    __builtin_amdgcn_s_setprio(0);
  }

  // Merge lsum across halves (pL reused as 512 x float4 exchange buffer).
  __syncthreads();  // full drain OK here (once; also clears leftover prefetch)
  float4* xL = (float4*)pL;
  xL[wave * 64 + lane] = float4{lsum[0], lsum[1], lsum[2], lsum[3]};
  __syncthreads();
  const float4 ol = xL[(wave ^ 4) * 64 + lane];
  float inv[4];
  inv[0] = 1.0f / (lsum[0] + ol.x);
  inv[1] = 1.0f / (lsum[1] + ol.y);
  inv[2] = 1.0f / (lsum[2] + ol.z);
  inv[3] = 1.0f / (lsum[3] + ol.w);

#pragma unroll
  for (int m = 0; m < 8; m++) {
    const int c = (h * 8 + m) * 16 + rl;
#pragma unroll
    for (int r = 0; r < 4; r++) {
      const int j = j0 + w * 16 + (lane >> 4) * 4 + r;
      rT[(long)j * 256 + c] = f2bf(oacc[m][r] * inv[r]);
    }
  }
#undef STAGE_QV
}

// Convert the six 256x256 fp32 weight matrices to bf16 (contiguous dst).
__global__ __launch_bounds__(256) void convert6(
    const float* __restrict__ a0, const float* __restrict__ a1,
    const float* __restrict__ a2, const float* __restrict__ a3,
    const float* __restrict__ a4, const float* __restrict__ a5,
    unsigned short* __restrict__ dst) {
  int idx = blockIdx.x * 256 + threadIdx.x;
  int m = idx >> 16, r = idx & 65535;
  const float* s;
  switch (m) {
    case 0: s = a0; break;
    case 1: s = a1; break;
    case 2: s = a2; break;
    case 3: s = a3; break;
    case 4: s = a4; break;
    default: s = a5; break;
  }
  dst[idx] = f2bf(s[r]);
}

// Sinusoidal table: embed[t,d] = sin/cos(t * 10000^(-d/128)), d even->sin.
__global__ __launch_bounds__(256) void embed_k(unsigned short* __restrict__ e) {
  int idx = blockIdx.x * 256 + threadIdx.x;
  int t = idx >> 8, d = idx & 255;
  float freq = powf(10000.0f, -(float)d * (1.0f / 128.0f));
  float w = (float)t * freq;
  float r = (d & 1) ? cosf(w) : sinf(w);
  e[idx] = f2bf(r);
}

// x [4][256][4096] fp32  ->  XT [4][4096][256] bf16
__global__ void transpose_x(const float* __restrict__ x,
                            unsigned short* __restrict__ xt) {
  __shared__ float tile[32][33];
  const int b = blockIdx.z;
  const int s0 = blockIdx.x * 32, c0 = blockIdx.y * 32;
  const int tx = threadIdx.x, ty = threadIdx.y;
  const float* xb = x + (long)b * 256 * 4096;
#pragma unroll
  for (int r = 0; r < 32; r += 8)
    tile[ty + r][tx] = xb[(long)(c0 + ty + r) * 4096 + s0 + tx];
  __syncthreads();
  unsigned short* xtb = xt + (long)b * 4096 * 256;
#pragma unroll
  for (int r = 0; r < 32; r += 8)
    xtb[(long)(s0 + ty + r) * 256 + c0 + tx] = f2bf(tile[tx][ty + r]);
}

// ---------------------------------------------------------------------------
extern "C" void kernel_launch(void* const* d_in, const int* in_sizes, int n_in,
                              void* d_out, int out_size, void* d_ws,
                              size_t ws_size, hipStream_t stream) {
  const float* x  = (const float*)d_in[0];
  const float* wq = (const float*)d_in[1];
  const float* bq = (const float*)d_in[2];
  const float* wk = (const float*)d_in[3];
  const float* bk = (const float*)d_in[4];
  const float* wv = (const float*)d_in[5];
  const float* bv = (const float*)d_in[6];
  const float* wo = (const float*)d_in[7];
  const float* bo = (const float*)d_in[8];
  const float* w1 = (const float*)d_in[9];
  const float* b1 = (const float*)d_in[10];
  const float* w2 = (const float*)d_in[11];
  const float* b2 = (const float*)d_in[12];
  float* out = (float*)d_out;

  char* ws = (char*)d_ws;
  unsigned short* wqb = (unsigned short*)(ws + 0);         // 6x 256x256 bf16
  unsigned short* wkb = (unsigned short*)(ws + 131072);
  unsigned short* wvb = (unsigned short*)(ws + 262144);
  unsigned short* wob = (unsigned short*)(ws + 393216);
  unsigned short* w1b = (unsigned short*)(ws + 524288);
  unsigned short* w2b = (unsigned short*)(ws + 655360);
  unsigned short* emb = (unsigned short*)(ws + 786432);    // [4096][256] bf16
  unsigned short* h1b = (unsigned short*)(ws + 2883584);   // [4096][256] bf16
  float*          peF = (float*)(ws + 4980736);            // [4096][256] fp32
  unsigned short* XT  = (unsigned short*)(ws + 9175040);   // [4][4096][256]
  unsigned short* qT  = (unsigned short*)(ws + 17563648);  // [4][4096][256]
  unsigned short* kT  = (unsigned short*)(ws + 25952256);  // [4][4096][256]
  unsigned short* vB  = (unsigned short*)(ws + 34340864);  // [4][256][4096]
  unsigned short* rT  = (unsigned short*)(ws + 42729472);  // [4][4096][256]
  (void)ws_size; (void)in_sizes; (void)n_in; (void)out_size;

  const dim3 B256(256);
  const long S = 1048576;  // 4096*256 (= 256*4096) element batch stride

  convert6<<<1536, B256, 0, stream>>>(wq, wk, wv, wo, w1, w2, wqb);
  embed_k<<<4096, B256, 0, stream>>>(emb);
  // pe MLP: h1 = silu(embed @ w1^T + b1); peF = h1 @ w2^T + b2  (fp32 out)
  gemm_nt<1, 2, 0, 1><<<dim3(32, 2, 1), B256, 0, stream>>>(
      emb, w1b, h1b, 256, 256, 256, 0, 0, 0, b1, nullptr, 1.0f);
  gemm_nt<0, 2, 0, 0><<<dim3(32, 2, 1), B256, 0, stream>>>(
      h1b, w2b, peF, 256, 256, 256, 0, 0, 0, b2, nullptr, 1.0f);
  transpose_x<<<dim3(128, 8, 4), dim3(32, 8), 0, stream>>>(x, XT);
  // qT[s,o] = XT.wq + bq[o] + pe[o*4096+s]   (pe mode 2: col-major index)
  gemm_nt<1, 2, 2, 0><<<dim3(32, 2, 4), B256, 0, stream>>>(
      XT, wqb, qT, 256, 256, 256, S, 0, S, bq, peF, 1.0f);
  gemm_nt<1, 2, 2, 0><<<dim3(32, 2, 4), B256, 0, stream>>>(
      XT, wkb, kT, 256, 256, 256, S, 0, S, bk, peF, 1.0f);
  // v[o,s] = wv.XT + bv[o] + pe[o*4096+s]    (pe mode 1: row-major index)
  gemm_nt<1, 1, 1, 0><<<dim3(2, 32, 4), B256, 0, stream>>>(
      wvb, XT, vB, 256, 4096, 256, 0, S, S, bv, peF, 1.0f);

  // Fused attention: logits + softmax(axis i) + PV, no HBM intermediates.
  flash_attn<<<256, dim3(512), 0, stream>>>(qT, kT, vB, rT);

  // out[o,s] = wout . resT + b_out[o]  (fp32 -> d_out)
  gemm_nt<0, 1, 0, 0><<<dim3(2, 32, 4), B256, 0, stream>>>(
      wob, rT, out, 256, 4096, 256, 0, S, S, bo, nullptr, 1.0f);
}

// Round 7
// 179.960 us; speedup vs baseline: 1.2736x; 1.2736x over previous
//
#include <hip/hip_runtime.h>
#include <cstdint>

// ---------------------------------------------------------------------------
// SAGAN self-attention block, bf16-MFMA pipeline, flash-fused attention.
// GEMMs are NT form: C[m,n] = sum_k Arow[m][k] * Brow[n][k].
// Verified fragment conventions (R2-passing gemm):
//   A-frag: lane holds A[row = lane&15][k = (lane>>4)*8 + q], q=0..7
//   B-frag: lane holds B[col = lane&15][k = (lane>>4)*8 + q]
//   C/D:    lane holds C[row = (lane>>4)*4 + r][col = lane&15], r=0..3
// ---------------------------------------------------------------------------

typedef short s8v __attribute__((ext_vector_type(8)));   // 8 bf16 bits (4 VGPR)
typedef float f32x4 __attribute__((ext_vector_type(4)));

#define DEVI static __device__ __forceinline__

DEVI unsigned short f2bf(float f) {
  union { float f; uint32_t u; } x; x.f = f;
  uint32_t u = x.u;
  return (unsigned short)((u + 0x7fffu + ((u >> 16) & 1u)) >> 16);  // RNE
}

DEVI void gl_lds16(const void* g, void* l) {
  // async global->LDS, 16B per lane; LDS dest must be wave-uniform base.
  __builtin_amdgcn_global_load_lds(
      (const __attribute__((address_space(1))) void*)g,
      (__attribute__((address_space(3))) void*)l,
      16, 0, 0);
}

// Stage a [64 rows][32 k] bf16 tile (4KB), linear LDS layout (gemm_nt).
DEVI void stage(const unsigned short* src, int ld, unsigned short* lds, int t) {
  gl_lds16(src + (long)(t >> 2) * ld + (t & 3) * 8, lds + (t >> 6) * 512);
}

// Swizzled stage: LDS slot (row, chunk c) holds global chunk c ^ ((row>>1)&3).
// Achieved by pre-swizzling the per-lane GLOBAL source (LDS dest stays linear,
// as global_load_lds requires). Readers use ksw = ((lane>>4)^((rl>>1)&3))<<3.
DEVI void stage_s(const unsigned short* src, int ld, unsigned short* lds,
                  int tt) {
  const int tr = tt >> 2, c = tt & 3;
  const int sc = (c ^ ((tr >> 1) & 3)) * 8;
  gl_lds16(src + (long)tr * ld + sc, lds + (tt >> 6) * 512);
}

// ---------------------------------------------------------------------------
// NT GEMM: 128x128 tile, 4 waves (2x2), each wave 64x64 = 4x4 frags of
// 16x16x32 bf16 MFMA. (Unchanged from R2/R3 passing version.)
// ---------------------------------------------------------------------------
template <int OBF, int BIAS, int PEM, int SILU>
__global__ __launch_bounds__(256) void gemm_nt(
    const unsigned short* __restrict__ A, const unsigned short* __restrict__ B,
    void* __restrict__ Cp, int K, int N, int ld, long sA, long sB, long sC,
    const float* __restrict__ bias, const float* __restrict__ pe, float scale) {
  const int bz = blockIdx.z;
  const unsigned short* Ab = A + (long)bz * sA;
  const unsigned short* Bb = B + (long)bz * sB;
  const int m0 = blockIdx.x * 128, n0 = blockIdx.y * 128;
  __shared__ __align__(16) unsigned short As[4096], Bs[4096];  // [128][32]
  const int t = threadIdx.x;
  const int wave = t >> 6, lane = t & 63;
  const int wr = wave >> 1, wc = wave & 1;

  f32x4 acc[4][4];
#pragma unroll
  for (int i = 0; i < 4; i++)
#pragma unroll
    for (int j = 0; j < 4; j++) acc[i][j] = f32x4{0.f, 0.f, 0.f, 0.f};

  const int rl = lane & 15, kp = (lane >> 4) * 8;

  for (int k0 = 0; k0 < K; k0 += 32) {
    stage(Ab + (long)m0 * ld + k0, ld, As, t);
    stage(Ab + (long)(m0 + 64) * ld + k0, ld, As + 2048, t);
    stage(Bb + (long)n0 * ld + k0, ld, Bs, t);
    stage(Bb + (long)(n0 + 64) * ld + k0, ld, Bs + 2048, t);
    __syncthreads();  // drains vmcnt before barrier -> LDS valid

    s8v af[4], bfr[4];
#pragma unroll
    for (int i = 0; i < 4; i++)
      af[i] = *(const s8v*)(As + (wr * 64 + i * 16 + rl) * 32 + kp);
#pragma unroll
    for (int j = 0; j < 4; j++)
      bfr[j] = *(const s8v*)(Bs + (wc * 64 + j * 16 + rl) * 32 + kp);
#pragma unroll
    for (int i = 0; i < 4; i++)
#pragma unroll
      for (int j = 0; j < 4; j++)
        acc[i][j] = __builtin_amdgcn_mfma_f32_16x16x32_bf16(af[i], bfr[j],
                                                            acc[i][j], 0, 0, 0);
    __syncthreads();
  }

  const long cb = (long)bz * sC;
#pragma unroll
  for (int i = 0; i < 4; i++) {
    const int r0 = m0 + wr * 64 + i * 16 + (lane >> 4) * 4;
#pragma unroll
    for (int j = 0; j < 4; j++) {
      const int col = n0 + wc * 64 + j * 16 + (lane & 15);
#pragma unroll
      for (int r = 0; r < 4; r++) {
        const int row = r0 + r;
        float val = acc[i][j][r] * scale;
        if (BIAS == 1) val += bias[row];
        if (BIAS == 2) val += bias[col];
        if (PEM == 1) val += pe[(long)row * 4096 + col];
        if (PEM == 2) val += pe[(long)col * 4096 + row];
        if (SILU) val = val / (1.0f + __expf(-val));
        const long ci = cb + (long)row * N + col;
        if (OBF)
          ((unsigned short*)Cp)[ci] = f2bf(val);
        else
          ((float*)Cp)[ci] = val;
      }
    }
  }
}

// ---------------------------------------------------------------------------
// Flash-fused attention v4: 256 blocks x 512 thr. Block = (jblk, ihalf, b):
// 128 j-rows, i-range [ihalf*2048, +2048), 32 i-tiles of 64.
// Each wave owns 16 j-rows and computes the FULL 64-i strip -> P is
// wave-private (LDS bounce same-wave, no mid barrier). lsum reduction is
// deferred to after the loop (per-lane partials; sum is commutative).
// One __syncthreads per iter (drains staging; protects buffer reuse).
// Outputs UNNORMALIZED O-partials (fp32) + lsum partials; combine_o merges
// the two i-halves and normalizes (softmax-without-max is exactly additive).
// ---------------------------------------------------------------------------
__global__ __launch_bounds__(512, 2) void flash_attn(
    const unsigned short* __restrict__ qTp, const unsigned short* __restrict__ kTp,
    const unsigned short* __restrict__ vBp, float* __restrict__ oPart,
    float* __restrict__ lPart) {
  const int bid = blockIdx.x;
  // XCD-aware mapping: xcd = bid&7 -> (b, ihalf); per-XCD L2 set ~4MB.
  const int xcd = bid & 7;
  const int b = xcd >> 1, ihalf = xcd & 1;
  const int j0 = (bid >> 3) * 128;
  const long S = 1048576;
  const long ibase = (long)ihalf * 2048;
  const unsigned short* q = qTp + (long)b * S;
  const unsigned short* k = kTp + (long)b * S;
  const unsigned short* v = vBp + (long)b * S;
  const int ob = b * 2 + ihalf;  // output plane

  __shared__ __align__(16) unsigned short qL[2][16384];  // [buf][8s][64 i][32]
  __shared__ __align__(16) unsigned short vL[2][16384];  // [buf][4cg][2ki][64c][32]
  __shared__ __align__(16) unsigned short pL[10240];     // [8w][2ki][16 j][40]

  const int t = threadIdx.x;
  const int wave = t >> 6, lane = t & 63;
  const int rl = lane & 15, g = lane >> 4;
  const int kp = g * 8;
  const int ksw = ((g ^ ((rl >> 1) & 3)) << 3);          // swizzled k-offset
  const int th = t >> 8, tt = t & 255;                   // staging split
  unsigned short* pLw = pL + wave * 1280;                // wave-private P

  // K-strip -> registers: wave owns rows j0 + wave*16 + rl.
  const unsigned short* krow = k + (long)(j0 + wave * 16 + rl) * 256 + kp;
  s8v kreg[8];
#pragma unroll
  for (int s = 0; s < 8; s++) kreg[s] = *(const s8v*)(krow + s * 32);

  f32x4 oacc[16];
#pragma unroll
  for (int f = 0; f < 16; f++) oacc[f] = f32x4{0.f, 0.f, 0.f, 0.f};
  float plsum[4] = {0.f, 0.f, 0.f, 0.f};

  // Stage (qL,vL) for i-tile `it` into buffer `bf`: 8 gl_lds per thread.
#define STAGE_QV(it, bf)                                                     \
  {                                                                          \
    const long i0_ = ibase + (long)(it) * 64;                                \
    _Pragma("unroll") for (int ss = 0; ss < 4; ss++) {                       \
      const int s_ = ss * 2 + th;                                            \
      stage_s(q + i0_ * 256 + s_ * 32, 256, qL[bf] + s_ * 2048, tt);         \
    }                                                                        \
    _Pragma("unroll") for (int ss = 0; ss < 4; ss++) {                       \
      const int vt_ = ss * 2 + th;                                           \
      stage_s(v + (long)((vt_ >> 1) * 64) * 4096 + i0_ + (vt_ & 1) * 32,     \
              4096, vL[bf] + vt_ * 2048, tt);                                \
    }                                                                        \
  }

  STAGE_QV(0, 0)

  for (int n = 0; n < 32; ++n) {
    const int cur = n & 1;
    __syncthreads();  // buf[cur] staged; all waves done with buf[cur^1]
    if (n + 1 < 32) STAGE_QV(n + 1, cur ^ 1)  // overlaps with compute

    // QK^T: full 64-i strip for this wave's 16 j-rows. 32 MFMA.
    f32x4 sa[4];
#pragma unroll
    for (int f = 0; f < 4; f++) sa[f] = f32x4{0.f, 0.f, 0.f, 0.f};
#pragma unroll
    for (int s = 0; s < 8; s++) {
      const unsigned short* qb = qL[cur] + s * 2048;
#pragma unroll
      for (int f = 0; f < 4; f++) {
        s8v bf = *(const s8v*)(qb + (f * 16 + rl) * 32 + ksw);
        sa[f] = __builtin_amdgcn_mfma_f32_16x16x32_bf16(kreg[s], bf, sa[f],
                                                        0, 0, 0);
      }
    }

    // Static-max softmax, deferred-lsum: P = exp(s/16), per-lane partials.
    // P -> wave-private LDS in A-frag layout, padded row stride 40.
#pragma unroll
    for (int f = 0; f < 4; f++) {
#pragma unroll
      for (int r = 0; r < 4; r++) {
        const float p = __expf(sa[f][r] * 0.0625f);
        plsum[r] += p;
        pLw[(f >> 1) * 640 + (g * 4 + r) * 40 + (f & 1) * 16 + rl] = f2bf(p);
      }
    }

    // PV (same-wave pL read; compiler inserts the lgkmcnt dependency).
#pragma unroll
    for (int ki = 0; ki < 2; ki++) {
      s8v pa = *(const s8v*)(pLw + ki * 640 + rl * 40 + kp);
#pragma unroll
      for (int m = 0; m < 16; m++) {
        s8v vb = *(const s8v*)(vL[cur] + (m >> 2) * 4096 + ki * 2048 +
                               ((m & 3) * 16 + rl) * 32 + ksw);
        oacc[m] = __builtin_amdgcn_mfma_f32_16x16x32_bf16(pa, vb, oacc[m],
                                                          0, 0, 0);
      }
    }
  }

  // Deferred lsum: one butterfly reduce over the 16-lane i-groups.
#pragma unroll
  for (int r = 0; r < 4; r++) {
    plsum[r] += __shfl_xor(plsum[r], 1);
    plsum[r] += __shfl_xor(plsum[r], 2);
    plsum[r] += __shfl_xor(plsum[r], 4);
    plsum[r] += __shfl_xor(plsum[r], 8);
  }
  if (rl == 0) {
#pragma unroll
    for (int r = 0; r < 4; r++)
      lPart[(long)ob * 4096 + j0 + wave * 16 + g * 4 + r] = plsum[r];
  }

  // Unnormalized O partials -> HBM fp32.
  float* op = oPart + (long)ob * 1048576;
#pragma unroll
  for (int m = 0; m < 16; m++) {
    const int c = m * 16 + rl;
#pragma unroll
    for (int r = 0; r < 4; r++) {
      const int j = j0 + wave * 16 + g * 4 + r;
      op[(long)j * 256 + c] = oacc[m][r];
    }
  }
#undef STAGE_QV
}

// Combine the two i-half partials: rT[b][j][c] = (O0+O1)/(l0+l1) -> bf16.
__global__ __launch_bounds__(256) void combine_o(
    const float* __restrict__ oPart, const float* __restrict__ lPart,
    unsigned short* __restrict__ rT) {
  const long idx = (long)blockIdx.x * 256 + threadIdx.x;  // float4 units
  const int c4 = idx & 63;
  const int j = (idx >> 6) & 4095;
  const int b = idx >> 18;
  const long p0 = ((long)(b * 2) * 1048576 + (long)j * 256) / 4 + c4;
  const float4 a = ((const float4*)oPart)[p0];
  const float4 d = ((const float4*)oPart)[p0 + 262144];
  const float l = lPart[(long)(b * 2) * 4096 + j] +
                  lPart[(long)(b * 2 + 1) * 4096 + j];
  const float inv = 1.0f / l;
  ushort4 o;
  o.x = f2bf((a.x + d.x) * inv);
  o.y = f2bf((a.y + d.y) * inv);
  o.z = f2bf((a.z + d.z) * inv);
  o.w = f2bf((a.w + d.w) * inv);
  ((ushort4*)rT)[(long)b * 262144 + (long)j * 64 + c4] = o;
}

// Convert the six 256x256 fp32 weight matrices to bf16 (contiguous dst).
__global__ __launch_bounds__(256) void convert6(
    const float* __restrict__ a0, const float* __restrict__ a1,
    const float* __restrict__ a2, const float* __restrict__ a3,
    const float* __restrict__ a4, const float* __restrict__ a5,
    unsigned short* __restrict__ dst) {
  int idx = blockIdx.x * 256 + threadIdx.x;
  int m = idx >> 16, r = idx & 65535;
  const float* s;
  switch (m) {
    case 0: s = a0; break;
    case 1: s = a1; break;
    case 2: s = a2; break;
    case 3: s = a3; break;
    case 4: s = a4; break;
    default: s = a5; break;
  }
  dst[idx] = f2bf(s[r]);
}

// Sinusoidal table: embed[t,d] = sin/cos(t * 10000^(-d/128)), d even->sin.
__global__ __launch_bounds__(256) void embed_k(unsigned short* __restrict__ e) {
  int idx = blockIdx.x * 256 + threadIdx.x;
  int t = idx >> 8, d = idx & 255;
  float freq = powf(10000.0f, -(float)d * (1.0f / 128.0f));
  float w = (float)t * freq;
  float r = (d & 1) ? cosf(w) : sinf(w);
  e[idx] = f2bf(r);
}

// x [4][256][4096] fp32  ->  XT [4][4096][256] bf16
__global__ void transpose_x(const float* __restrict__ x,
                            unsigned short* __restrict__ xt) {
  __shared__ float tile[32][33];
  const int b = blockIdx.z;
  const int s0 = blockIdx.x * 32, c0 = blockIdx.y * 32;
  const int tx = threadIdx.x, ty = threadIdx.y;
  const float* xb = x + (long)b * 256 * 4096;
#pragma unroll
  for (int r = 0; r < 32; r += 8)
    tile[ty + r][tx] = xb[(long)(c0 + ty + r) * 4096 + s0 + tx];
  __syncthreads();
  unsigned short* xtb = xt + (long)b * 4096 * 256;
#pragma unroll
  for (int r = 0; r < 32; r += 8)
    xtb[(long)(s0 + ty + r) * 256 + c0 + tx] = f2bf(tile[tx][ty + r]);
}

// ---------------------------------------------------------------------------
extern "C" void kernel_launch(void* const* d_in, const int* in_sizes, int n_in,
                              void* d_out, int out_size, void* d_ws,
                              size_t ws_size, hipStream_t stream) {
  const float* x  = (const float*)d_in[0];
  const float* wq = (const float*)d_in[1];
  const float* bq = (const float*)d_in[2];
  const float* wk = (const float*)d_in[3];
  const float* bk = (const float*)d_in[4];
  const float* wv = (const float*)d_in[5];
  const float* bv = (const float*)d_in[6];
  const float* wo = (const float*)d_in[7];
  const float* bo = (const float*)d_in[8];
  const float* w1 = (const float*)d_in[9];
  const float* b1 = (const float*)d_in[10];
  const float* w2 = (const float*)d_in[11];
  const float* b2 = (const float*)d_in[12];
  float* out = (float*)d_out;

  char* ws = (char*)d_ws;
  unsigned short* wqb = (unsigned short*)(ws + 0);         // 6x 256x256 bf16
  unsigned short* wkb = (unsigned short*)(ws + 131072);
  unsigned short* wvb = (unsigned short*)(ws + 262144);
  unsigned short* wob = (unsigned short*)(ws + 393216);
  unsigned short* w1b = (unsigned short*)(ws + 524288);
  unsigned short* w2b = (unsigned short*)(ws + 655360);
  unsigned short* emb = (unsigned short*)(ws + 786432);    // [4096][256] bf16
  unsigned short* h1b = (unsigned short*)(ws + 2883584);   // [4096][256] bf16
  float*          peF = (float*)(ws + 4980736);            // [4096][256] fp32
  unsigned short* XT  = (unsigned short*)(ws + 9175040);   // [4][4096][256]
  unsigned short* qT  = (unsigned short*)(ws + 17563648);  // [4][4096][256]
  unsigned short* kT  = (unsigned short*)(ws + 25952256);  // [4][4096][256]
  unsigned short* vB  = (unsigned short*)(ws + 34340864);  // [4][256][4096]
  unsigned short* rT  = (unsigned short*)(ws + 42729472);  // [4][4096][256]
  float*          oP  = (float*)(ws + 51118080);           // [8][4096][256] f32
  float*          lP  = (float*)(ws + 84672512);           // [8][4096] f32
  (void)ws_size; (void)in_sizes; (void)n_in; (void)out_size;

  const dim3 B256(256);
  const long S = 1048576;  // 4096*256 (= 256*4096) element batch stride

  convert6<<<1536, B256, 0, stream>>>(wq, wk, wv, wo, w1, w2, wqb);
  embed_k<<<4096, B256, 0, stream>>>(emb);
  // pe MLP: h1 = silu(embed @ w1^T + b1); peF = h1 @ w2^T + b2  (fp32 out)
  gemm_nt<1, 2, 0, 1><<<dim3(32, 2, 1), B256, 0, stream>>>(
      emb, w1b, h1b, 256, 256, 256, 0, 0, 0, b1, nullptr, 1.0f);
  gemm_nt<0, 2, 0, 0><<<dim3(32, 2, 1), B256, 0, stream>>>(
      h1b, w2b, peF, 256, 256, 256, 0, 0, 0, b2, nullptr, 1.0f);
  transpose_x<<<dim3(128, 8, 4), dim3(32, 8), 0, stream>>>(x, XT);
  // qT[s,o] = XT.wq + bq[o] + pe[o*4096+s]   (pe mode 2: col-major index)
  gemm_nt<1, 2, 2, 0><<<dim3(32, 2, 4), B256, 0, stream>>>(
      XT, wqb, qT, 256, 256, 256, S, 0, S, bq, peF, 1.0f);
  gemm_nt<1, 2, 2, 0><<<dim3(32, 2, 4), B256, 0, stream>>>(
      XT, wkb, kT, 256, 256, 256, S, 0, S, bk, peF, 1.0f);
  // v[o,s] = wv.XT + bv[o] + pe[o*4096+s]    (pe mode 1: row-major index)
  gemm_nt<1, 1, 1, 0><<<dim3(2, 32, 4), B256, 0, stream>>>(
      wvb, XT, vB, 256, 4096, 256, 0, S, S, bv, peF, 1.0f);

  // Fused attention: logits + softmax(axis i) + PV; i split across 2 blocks.
  flash_attn<<<256, dim3(512), 0, stream>>>(qT, kT, vB, oP, lP);
  combine_o<<<4096, B256, 0, stream>>>(oP, lP, rT);

  // out[o,s] = wout . resT + b_out[o]  (fp32 -> d_out)
  gemm_nt<0, 1, 0, 0><<<dim3(2, 32, 4), B256, 0, stream>>>(
      wob, rT, out, 256, 4096, 256, 0, S, S, bo, nullptr, 1.0f);
}

// Round 8
// 171.358 us; speedup vs baseline: 1.3375x; 1.0502x over previous
//
#include <hip/hip_runtime.h>
#include <cstdint>

// ---------------------------------------------------------------------------
// SAGAN self-attention block, bf16-MFMA pipeline, flash-fused attention.
// GEMMs are NT form: C[m,n] = sum_k Arow[m][k] * Brow[n][k].
// Verified fragment conventions (R2-passing gemm):
//   A-frag: lane holds A[row = lane&15][k = (lane>>4)*8 + q], q=0..7
//   B-frag: lane holds B[col = lane&15][k = (lane>>4)*8 + q]
//   C/D:    lane holds C[row = (lane>>4)*4 + r][col = lane&15], r=0..3
// ---------------------------------------------------------------------------

typedef short s8v __attribute__((ext_vector_type(8)));   // 8 bf16 bits (4 VGPR)
typedef float f32x4 __attribute__((ext_vector_type(4)));

#define DEVI static __device__ __forceinline__

DEVI unsigned short f2bf(float f) {
  union { float f; uint32_t u; } x; x.f = f;
  uint32_t u = x.u;
  return (unsigned short)((u + 0x7fffu + ((u >> 16) & 1u)) >> 16);  // RNE
}

DEVI void gl_lds16(const void* g, void* l) {
  // async global->LDS, 16B per lane; LDS dest must be wave-uniform base.
  __builtin_amdgcn_global_load_lds(
      (const __attribute__((address_space(1))) void*)g,
      (__attribute__((address_space(3))) void*)l,
      16, 0, 0);
}

// Stage a [64 rows][32 k] bf16 tile (4KB), linear LDS layout (gemm_nt).
DEVI void stage(const unsigned short* src, int ld, unsigned short* lds, int t) {
  gl_lds16(src + (long)(t >> 2) * ld + (t & 3) * 8, lds + (t >> 6) * 512);
}

// ---------------------------------------------------------------------------
// NT GEMM: 128x128 tile, 4 waves (2x2), each wave 64x64 = 4x4 frags of
// 16x16x32 bf16 MFMA. (Unchanged from R2/R3 passing version.)
// ---------------------------------------------------------------------------
template <int OBF, int BIAS, int PEM, int SILU>
__global__ __launch_bounds__(256) void gemm_nt(
    const unsigned short* __restrict__ A, const unsigned short* __restrict__ B,
    void* __restrict__ Cp, int K, int N, int ld, long sA, long sB, long sC,
    const float* __restrict__ bias, const float* __restrict__ pe, float scale) {
  const int bz = blockIdx.z;
  const unsigned short* Ab = A + (long)bz * sA;
  const unsigned short* Bb = B + (long)bz * sB;
  const int m0 = blockIdx.x * 128, n0 = blockIdx.y * 128;
  __shared__ __align__(16) unsigned short As[4096], Bs[4096];  // [128][32]
  const int t = threadIdx.x;
  const int wave = t >> 6, lane = t & 63;
  const int wr = wave >> 1, wc = wave & 1;

  f32x4 acc[4][4];
#pragma unroll
  for (int i = 0; i < 4; i++)
#pragma unroll
    for (int j = 0; j < 4; j++) acc[i][j] = f32x4{0.f, 0.f, 0.f, 0.f};

  const int rl = lane & 15, kp = (lane >> 4) * 8;

  for (int k0 = 0; k0 < K; k0 += 32) {
    stage(Ab + (long)m0 * ld + k0, ld, As, t);
    stage(Ab + (long)(m0 + 64) * ld + k0, ld, As + 2048, t);
    stage(Bb + (long)n0 * ld + k0, ld, Bs, t);
    stage(Bb + (long)(n0 + 64) * ld + k0, ld, Bs + 2048, t);
    __syncthreads();  // drains vmcnt before barrier -> LDS valid

    s8v af[4], bfr[4];
#pragma unroll
    for (int i = 0; i < 4; i++)
      af[i] = *(const s8v*)(As + (wr * 64 + i * 16 + rl) * 32 + kp);
#pragma unroll
    for (int j = 0; j < 4; j++)
      bfr[j] = *(const s8v*)(Bs + (wc * 64 + j * 16 + rl) * 32 + kp);
#pragma unroll
    for (int i = 0; i < 4; i++)
#pragma unroll
      for (int j = 0; j < 4; j++)
        acc[i][j] = __builtin_amdgcn_mfma_f32_16x16x32_bf16(af[i], bfr[j],
                                                            acc[i][j], 0, 0, 0);
    __syncthreads();
  }

  const long cb = (long)bz * sC;
#pragma unroll
  for (int i = 0; i < 4; i++) {
    const int r0 = m0 + wr * 64 + i * 16 + (lane >> 4) * 4;
#pragma unroll
    for (int j = 0; j < 4; j++) {
      const int col = n0 + wc * 64 + j * 16 + (lane & 15);
#pragma unroll
      for (int r = 0; r < 4; r++) {
        const int row = r0 + r;
        float val = acc[i][j][r] * scale;
        if (BIAS == 1) val += bias[row];
        if (BIAS == 2) val += bias[col];
        if (PEM == 1) val += pe[(long)row * 4096 + col];
        if (PEM == 2) val += pe[(long)col * 4096 + row];
        if (SILU) val = val / (1.0f + __expf(-val));
        const long ci = cb + (long)row * N + col;
        if (OBF)
          ((unsigned short*)Cp)[ci] = f2bf(val);
        else
          ((float*)Cp)[ci] = val;
      }
    }
  }
}

// ---------------------------------------------------------------------------
// Flash-fused attention v5: 256 blocks x 512 thr. Block = (jblk, ihalf, b):
// 128 j-rows, i-range [ihalf*2048, +2048), 32 i-tiles of 64.
// Wave = (jq 0..3, ch 0..1): owns 32 j-rows (j0 + jq*32) and i-subhalf ch
// (32 of the tile's 64 i). QK B-frags read once per 2 j-MFMAs (q-traffic
// halved); PV v-frags read once per 2 j-MFMAs (v-traffic halved). P stays
// wave-private (no mid barrier). O/lsum partials over i-subhalves are merged
// across ch-pairs in an LDS epilogue; outputs unchanged vs v4 (oPart[8] +
// lPart[8], consumed by combine_o).
// ---------------------------------------------------------------------------
__global__ __launch_bounds__(512, 2) void flash_attn(
    const unsigned short* __restrict__ qTp, const unsigned short* __restrict__ kTp,
    const unsigned short* __restrict__ vBp, float* __restrict__ oPart,
    float* __restrict__ lPart) {
  const int bid = blockIdx.x;
  // XCD-aware mapping: xcd = bid&7 -> (b, ihalf); per-XCD L2 set ~4MB.
  const int xcd = bid & 7;
  const int b = xcd >> 1, ihalf = xcd & 1;
  const int j0 = (bid >> 3) * 128;
  const long S = 1048576;
  const long ibase = (long)ihalf * 2048;
  const unsigned short* q = qTp + (long)b * S;
  const unsigned short* k = kTp + (long)b * S;
  const unsigned short* v = vBp + (long)b * S;
  const int ob = b * 2 + ihalf;  // output plane

  // LDS: [0,64K) qL dbuf, [64K,128K) vL dbuf, [128K, +20480) pL.
  // Epilogue aliases: [0,128K) = O exchange (fp32), [128K,+512) = lsum exch.
  __shared__ __align__(16) unsigned char ldsb[151552];

  const int t = threadIdx.x;
  const int wave = t >> 6, lane = t & 63;
  const int jq = wave & 3, ch = wave >> 2;
  const int rl = lane & 15, g = lane >> 4;
  const int kp = g * 8;
  const int ksw = ((g ^ ((rl >> 1) & 3)) << 3);          // swizzled k-offset
  const int th = t >> 8, tt = t & 255;                   // staging split
  unsigned short* pL = (unsigned short*)(ldsb + 131072);
  unsigned short* pLw = pL + wave * 1280;                // [2 jf][16 j][40]

  // K-strip -> registers: wave owns rows j0 + jq*32 + jf*16 + rl.
  const unsigned short* krow = k + (long)(j0 + jq * 32 + rl) * 256 + kp;
  s8v kreg[2][8];
#pragma unroll
  for (int jf = 0; jf < 2; jf++)
#pragma unroll
    for (int s = 0; s < 8; s++)
      kreg[jf][s] = *(const s8v*)(krow + jf * 16 * 256 + s * 32);

  f32x4 oacc[2][16];
#pragma unroll
  for (int jf = 0; jf < 2; jf++)
#pragma unroll
    for (int cf = 0; cf < 16; cf++) oacc[jf][cf] = f32x4{0.f, 0.f, 0.f, 0.f};
  float plsum[2][4] = {{0.f, 0.f, 0.f, 0.f}, {0.f, 0.f, 0.f, 0.f}};

  // Pre-swizzled, pre-offset staging pointers (bumped per iter; source
  // swizzle: slot chunk c holds global chunk c ^ ((row>>1)&3); LDS linear).
  const int tr = tt >> 2, tc = tt & 3;
  const int sc = (tc ^ ((tr >> 1) & 3)) * 8;
  const unsigned short* qsrc[4];
  const unsigned short* vsrc[4];
  const int dsto = (tt >> 6) * 512;  // wave-uniform LDS sub-offset
#pragma unroll
  for (int ss = 0; ss < 4; ss++) {
    const int s_ = ss * 2 + th;
    qsrc[ss] = q + ibase * 256 + s_ * 32 + (long)tr * 256 + sc;
    vsrc[ss] = v + (long)((s_ >> 1) * 64) * 4096 + ibase + (s_ & 1) * 32 +
               (long)tr * 4096 + sc;
  }

#define STAGE_QV(bufsel)                                                     \
  {                                                                          \
    unsigned short* qD = (unsigned short*)(ldsb + ((bufsel) << 15));         \
    unsigned short* vD = (unsigned short*)(ldsb + 65536 + ((bufsel) << 15)); \
    _Pragma("unroll") for (int ss = 0; ss < 4; ss++) {                       \
      const int s_ = ss * 2 + th;                                            \
      gl_lds16(qsrc[ss], qD + s_ * 2048 + dsto);                             \
      gl_lds16(vsrc[ss], vD + s_ * 2048 + dsto);                             \
      qsrc[ss] += 16384;  /* next i-tile: +64*256 elems */                   \
      vsrc[ss] += 64;     /* next i-tile: +64 elems     */                   \
    }                                                                        \
  }

  STAGE_QV(0)

  for (int n = 0; n < 32; ++n) {
    const int cur = n & 1;
    __syncthreads();  // buf[cur] staged; all waves done with buf[cur^1]
    if (n + 1 < 32) STAGE_QV(cur ^ 1)  // overlaps with compute

    const unsigned short* qLb = (const unsigned short*)(ldsb + (cur << 15));
    const unsigned short* vLb =
        (const unsigned short*)(ldsb + 65536 + (cur << 15));

    // QK^T: own i-subhalf (32 i): 16 B-frag reads, 32 MFMA (2 jf x 2 if x 8s).
    f32x4 sa[2][2];
#pragma unroll
    for (int jf = 0; jf < 2; jf++)
#pragma unroll
      for (int f = 0; f < 2; f++) sa[jf][f] = f32x4{0.f, 0.f, 0.f, 0.f};
    const unsigned short* qbase = qLb + (ch * 32 + rl) * 32 + ksw;
#pragma unroll
    for (int s = 0; s < 8; s++) {
#pragma unroll
      for (int f = 0; f < 2; f++) {
        s8v bf = *(const s8v*)(qbase + s * 2048 + f * 512);
        sa[0][f] = __builtin_amdgcn_mfma_f32_16x16x32_bf16(kreg[0][s], bf,
                                                           sa[0][f], 0, 0, 0);
        sa[1][f] = __builtin_amdgcn_mfma_f32_16x16x32_bf16(kreg[1][s], bf,
                                                           sa[1][f], 0, 0, 0);
      }
    }

    // Static-max softmax (|logit| << 88), deferred lsum; P -> wave-private
    // LDS in A-frag layout, padded row stride 40 (<=2-way conflicts).
#pragma unroll
    for (int jf = 0; jf < 2; jf++)
#pragma unroll
      for (int f = 0; f < 2; f++)
#pragma unroll
        for (int r = 0; r < 4; r++) {
          const float p = __expf(sa[jf][f][r] * 0.0625f);
          plsum[jf][r] += p;
          pLw[jf * 640 + (g * 4 + r) * 40 + f * 16 + rl] = f2bf(p);
        }

    // PV over own i-subhalf (K=32): 16 v-frag reads, 32 MFMA (16 cf x 2 jf).
    s8v pa0 = *(const s8v*)(pLw + rl * 40 + kp);
    s8v pa1 = *(const s8v*)(pLw + 640 + rl * 40 + kp);
    const unsigned short* vbase = vLb + ch * 2048 + rl * 32 + ksw;
#pragma unroll
    for (int cf = 0; cf < 16; cf++) {
      s8v vb = *(const s8v*)(vbase + (cf >> 2) * 4096 + (cf & 3) * 512);
      oacc[0][cf] = __builtin_amdgcn_mfma_f32_16x16x32_bf16(pa0, vb,
                                                            oacc[0][cf], 0, 0, 0);
      oacc[1][cf] = __builtin_amdgcn_mfma_f32_16x16x32_bf16(pa1, vb,
                                                            oacc[1][cf], 0, 0, 0);
    }
  }

  // Deferred lsum: butterfly over the 16-lane i-groups.
#pragma unroll
  for (int jf = 0; jf < 2; jf++)
#pragma unroll
    for (int r = 0; r < 4; r++) {
      plsum[jf][r] += __shfl_xor(plsum[jf][r], 1);
      plsum[jf][r] += __shfl_xor(plsum[jf][r], 2);
      plsum[jf][r] += __shfl_xor(plsum[jf][r], 4);
      plsum[jf][r] += __shfl_xor(plsum[jf][r], 8);
    }

  // Merge ch-pairs (complementary i-subhalves) through LDS, then write
  // unnormalized O-partials + lsum partials (same outputs as v4).
  __syncthreads();  // loop LDS dead; safe to alias
  float* ex = (float*)ldsb;             // [4 jq][32 j][256 c]
  float* exl = (float*)(ldsb + 131072); // [4 jq][32 j]
  if (ch == 1) {
    float* exw = ex + jq * 8192;
#pragma unroll
    for (int jf = 0; jf < 2; jf++)
#pragma unroll
      for (int cf = 0; cf < 16; cf++)
#pragma unroll
        for (int r = 0; r < 4; r++)
          exw[(jf * 16 + g * 4 + r) * 256 + cf * 16 + rl] = oacc[jf][cf][r];
    if (rl == 0) {
#pragma unroll
      for (int jf = 0; jf < 2; jf++)
#pragma unroll
        for (int r = 0; r < 4; r++)
          exl[jq * 32 + jf * 16 + g * 4 + r] = plsum[jf][r];
    }
  }
  __syncthreads();
  if (ch == 0) {
    float* exw = ex + jq * 8192;
    float* op = oPart + (long)ob * 1048576;
#pragma unroll
    for (int jf = 0; jf < 2; jf++) {
      if (rl == 0) {
#pragma unroll
        for (int r = 0; r < 4; r++) {
          const int jl = jq * 32 + jf * 16 + g * 4 + r;
          lPart[(long)ob * 4096 + j0 + jl] = plsum[jf][r] + exl[jl];
        }
      }
#pragma unroll
      for (int cf = 0; cf < 16; cf++)
#pragma unroll
        for (int r = 0; r < 4; r++) {
          const int jl2 = jf * 16 + g * 4 + r;
          op[(long)(j0 + jq * 32 + jl2) * 256 + cf * 16 + rl] =
              oacc[jf][cf][r] + exw[jl2 * 256 + cf * 16 + rl];
        }
    }
  }
#undef STAGE_QV
}

// Combine the two i-half partials: rT[b][j][c] = (O0+O1)/(l0+l1) -> bf16.
__global__ __launch_bounds__(256) void combine_o(
    const float* __restrict__ oPart, const float* __restrict__ lPart,
    unsigned short* __restrict__ rT) {
  const long idx = (long)blockIdx.x * 256 + threadIdx.x;  // float4 units
  const int c4 = idx & 63;
  const int j = (idx >> 6) & 4095;
  const int b = idx >> 18;
  const long p0 = ((long)(b * 2) * 1048576 + (long)j * 256) / 4 + c4;
  const float4 a = ((const float4*)oPart)[p0];
  const float4 d = ((const float4*)oPart)[p0 + 262144];
  const float l = lPart[(long)(b * 2) * 4096 + j] +
                  lPart[(long)(b * 2 + 1) * 4096 + j];
  const float inv = 1.0f / l;
  ushort4 o;
  o.x = f2bf((a.x + d.x) * inv);
  o.y = f2bf((a.y + d.y) * inv);
  o.z = f2bf((a.z + d.z) * inv);
  o.w = f2bf((a.w + d.w) * inv);
  ((ushort4*)rT)[(long)b * 262144 + (long)j * 64 + c4] = o;
}

// Convert the six 256x256 fp32 weight matrices to bf16 (contiguous dst).
__global__ __launch_bounds__(256) void convert6(
    const float* __restrict__ a0, const float* __restrict__ a1,
    const float* __restrict__ a2, const float* __restrict__ a3,
    const float* __restrict__ a4, const float* __restrict__ a5,
    unsigned short* __restrict__ dst) {
  int idx = blockIdx.x * 256 + threadIdx.x;
  int m = idx >> 16, r = idx & 65535;
  const float* s;
  switch (m) {
    case 0: s = a0; break;
    case 1: s = a1; break;
    case 2: s = a2; break;
    case 3: s = a3; break;
    case 4: s = a4; break;
    default: s = a5; break;
  }
  dst[idx] = f2bf(s[r]);
}

// Sinusoidal table: embed[t,d] = sin/cos(t * 10000^(-d/128)), d even->sin.
__global__ __launch_bounds__(256) void embed_k(unsigned short* __restrict__ e) {
  int idx = blockIdx.x * 256 + threadIdx.x;
  int t = idx >> 8, d = idx & 255;
  float freq = powf(10000.0f, -(float)d * (1.0f / 128.0f));
  float w = (float)t * freq;
  float r = (d & 1) ? cosf(w) : sinf(w);
  e[idx] = f2bf(r);
}

// x [4][256][4096] fp32  ->  XT [4][4096][256] bf16
__global__ void transpose_x(const float* __restrict__ x,
                            unsigned short* __restrict__ xt) {
  __shared__ float tile[32][33];
  const int b = blockIdx.z;
  const int s0 = blockIdx.x * 32, c0 = blockIdx.y * 32;
  const int tx = threadIdx.x, ty = threadIdx.y;
  const float* xb = x + (long)b * 256 * 4096;
#pragma unroll
  for (int r = 0; r < 32; r += 8)
    tile[ty + r][tx] = xb[(long)(c0 + ty + r) * 4096 + s0 + tx];
  __syncthreads();
  unsigned short* xtb = xt + (long)b * 4096 * 256;
#pragma unroll
  for (int r = 0; r < 32; r += 8)
    xtb[(long)(s0 + ty + r) * 256 + c0 + tx] = f2bf(tile[tx][ty + r]);
}

// ---------------------------------------------------------------------------
extern "C" void kernel_launch(void* const* d_in, const int* in_sizes, int n_in,
                              void* d_out, int out_size, void* d_ws,
                              size_t ws_size, hipStream_t stream) {
  const float* x  = (const float*)d_in[0];
  const float* wq = (const float*)d_in[1];
  const float* bq = (const float*)d_in[2];
  const float* wk = (const float*)d_in[3];
  const float* bk = (const float*)d_in[4];
  const float* wv = (const float*)d_in[5];
  const float* bv = (const float*)d_in[6];
  const float* wo = (const float*)d_in[7];
  const float* bo = (const float*)d_in[8];
  const float* w1 = (const float*)d_in[9];
  const float* b1 = (const float*)d_in[10];
  const float* w2 = (const float*)d_in[11];
  const float* b2 = (const float*)d_in[12];
  float* out = (float*)d_out;

  char* ws = (char*)d_ws;
  unsigned short* wqb = (unsigned short*)(ws + 0);         // 6x 256x256 bf16
  unsigned short* wkb = (unsigned short*)(ws + 131072);
  unsigned short* wvb = (unsigned short*)(ws + 262144);
  unsigned short* wob = (unsigned short*)(ws + 393216);
  unsigned short* w1b = (unsigned short*)(ws + 524288);
  unsigned short* w2b = (unsigned short*)(ws + 655360);
  unsigned short* emb = (unsigned short*)(ws + 786432);    // [4096][256] bf16
  unsigned short* h1b = (unsigned short*)(ws + 2883584);   // [4096][256] bf16
  float*          peF = (float*)(ws + 4980736);            // [4096][256] fp32
  unsigned short* XT  = (unsigned short*)(ws + 9175040);   // [4][4096][256]
  unsigned short* qT  = (unsigned short*)(ws + 17563648);  // [4][4096][256]
  unsigned short* kT  = (unsigned short*)(ws + 25952256);  // [4][4096][256]
  unsigned short* vB  = (unsigned short*)(ws + 34340864);  // [4][256][4096]
  unsigned short* rT  = (unsigned short*)(ws + 42729472);  // [4][4096][256]
  float*          oP  = (float*)(ws + 51118080);           // [8][4096][256] f32
  float*          lP  = (float*)(ws + 84672512);           // [8][4096] f32
  (void)ws_size; (void)in_sizes; (void)n_in; (void)out_size;

  const dim3 B256(256);
  const long S = 1048576;  // 4096*256 (= 256*4096) element batch stride

  convert6<<<1536, B256, 0, stream>>>(wq, wk, wv, wo, w1, w2, wqb);
  embed_k<<<4096, B256, 0, stream>>>(emb);
  // pe MLP: h1 = silu(embed @ w1^T + b1); peF = h1 @ w2^T + b2  (fp32 out)
  gemm_nt<1, 2, 0, 1><<<dim3(32, 2, 1), B256, 0, stream>>>(
      emb, w1b, h1b, 256, 256, 256, 0, 0, 0, b1, nullptr, 1.0f);
  gemm_nt<0, 2, 0, 0><<<dim3(32, 2, 1), B256, 0, stream>>>(
      h1b, w2b, peF, 256, 256, 256, 0, 0, 0, b2, nullptr, 1.0f);
  transpose_x<<<dim3(128, 8, 4), dim3(32, 8), 0, stream>>>(x, XT);
  // qT[s,o] = XT.wq + bq[o] + pe[o*4096+s]   (pe mode 2: col-major index)
  gemm_nt<1, 2, 2, 0><<<dim3(32, 2, 4), B256, 0, stream>>>(
      XT, wqb, qT, 256, 256, 256, S, 0, S, bq, peF, 1.0f);
  gemm_nt<1, 2, 2, 0><<<dim3(32, 2, 4), B256, 0, stream>>>(
      XT, wkb, kT, 256, 256, 256, S, 0, S, bk, peF, 1.0f);
  // v[o,s] = wv.XT + bv[o] + pe[o*4096+s]    (pe mode 1: row-major index)
  gemm_nt<1, 1, 1, 0><<<dim3(2, 32, 4), B256, 0, stream>>>(
      wvb, XT, vB, 256, 4096, 256, 0, S, S, bv, peF, 1.0f);

  // Fused attention: logits + softmax(axis i) + PV; i split across 2 blocks.
  flash_attn<<<256, dim3(512), 0, stream>>>(qT, kT, vB, oP, lP);
  combine_o<<<4096, B256, 0, stream>>>(oP, lP, rT);

  // out[o,s] = wout . resT + b_out[o]  (fp32 -> d_out)
  gemm_nt<0, 1, 0, 0><<<dim3(2, 32, 4), B256, 0, stream>>>(
      wob, rT, out, 256, 4096, 256, 0, S, S, bo, nullptr, 1.0f);
}